// Round 1
// baseline (653.051 us; speedup 1.0000x reference)
//
#include <hip/hip_runtime.h>
#include <math.h>

// Problem constants (from reference)
#define N_CELLS 50000
#define C_CLS   30
#define G_GENES 1000
#define E_EDGES 800000

// Main row-kernel tiling: 64 rows/block, 128 threads, thread tile 8 rows x 5 cols,
// 80 output cols = 30(A) + 30(B) + 8(xl) + 8(xr) + 4(pad, zero coef)
#define ROWS_PER_BLK 64
#define KT       40     // gene tile (1000 = 25 * 40)
#define NCOLS    80
#define TSTRIDE  41     // LDS tile stride (padded: conflict-free reads)
#define OSTRIDE  81     // LDS output buffer stride

// ---- order-preserving float<->uint encoding for atomic max on floats ----
__device__ __forceinline__ unsigned fenc(float x) {
    unsigned u = __float_as_uint(x);
    return (u & 0x80000000u) ? ~u : (u | 0x80000000u);
}
__device__ __forceinline__ float fdec(unsigned u) {
    return (u & 0x80000000u) ? __uint_as_float(u & 0x7fffffffu) : __uint_as_float(~u);
}

__device__ __forceinline__ float lrelu02(float v) { return v > 0.f ? v : 0.2f * v; }

// ---------------------------------------------------------------------------
// K0: build packed Coef[80][1000] and D[30] = sum_g Mu^2/Var
// rows 0-29: 1/Var ; 30-59: Mu/Var ; 60-67: Wl ; 68-75: Wr ; 76-79: 0
// ---------------------------------------------------------------------------
__global__ void prep_kernel(const float* __restrict__ Mu, const float* __restrict__ Var,
                            const float* __restrict__ Wl, const float* __restrict__ Wr,
                            float* __restrict__ Coef, float* __restrict__ Dvec) {
    const int r = blockIdx.x;
    const int t = threadIdx.x;
    __shared__ float red[256];
    float dacc = 0.f;
    for (int g = t; g < G_GENES; g += 256) {
        float v;
        if (r < 30) {
            float iv = 1.0f / Var[r * G_GENES + g];
            float mu = Mu[r * G_GENES + g];
            v = iv;
            dacc += mu * mu * iv;
        } else if (r < 60) {
            int c = r - 30;
            v = Mu[c * G_GENES + g] / Var[c * G_GENES + g];
        } else if (r < 68) {
            v = Wl[(r - 60) * G_GENES + g];
        } else if (r < 76) {
            v = Wr[(r - 68) * G_GENES + g];
        } else {
            v = 0.f;
        }
        Coef[r * G_GENES + g] = v;
    }
    if (r < 30) {
        red[t] = dacc;
        __syncthreads();
        for (int s = 128; s > 0; s >>= 1) {
            if (t < s) red[t] += red[t + s];
            __syncthreads();
        }
        if (t == 0) Dvec[r] = red[0];
    }
}

// ---------------------------------------------------------------------------
// K1: per-row heavy kernel.
// Phase 1: tiled "GEMM": acc[n, j] = sum_g feat(n,g) * Coef[j,g]
//          where feat = X^2 for j<30 (A part), X otherwise.
// Phase 2: softmax(W row) -> P, logP; F combine -> ll atomic; xl/xr +bias -> ws
// ---------------------------------------------------------------------------
__global__ __launch_bounds__(128) void main_rows_kernel(
    const float* __restrict__ X, const float* __restrict__ W,
    const float* __restrict__ S, const float* __restrict__ bl,
    const float* __restrict__ br, const float* __restrict__ Coef,
    const float* __restrict__ Dvec,
    float* __restrict__ out,          // [0]=ll, [1]=ce, [2..] = P row-major
    float* __restrict__ logP, float* __restrict__ xl, float* __restrict__ xr)
{
    __shared__ float smem[8528];          // 34.1 KB
    float* Xt  = smem;                    // [64][41]
    float* Xt2 = smem + 2624;             // [64][41] (X^2)
    float* Ct  = smem + 5248;             // [80][41]

    const int t = threadIdx.x;
    const int rowbase = blockIdx.x * ROWS_PER_BLK;
    const int rg = t >> 4;                // 0..7  -> rows rg*8 .. rg*8+7
    const int cg = t & 15;                // 0..15 -> cols cg*5 .. cg*5+4
    const bool isA = (cg < 6);            // cols 0..29 consume X^2

    float acc[8][5];
#pragma unroll
    for (int i = 0; i < 8; i++)
#pragma unroll
        for (int j = 0; j < 5; j++) acc[i][j] = 0.f;

    for (int kt = 0; kt < G_GENES; kt += KT) {
        __syncthreads();
        // stage X tile (64 rows x 40 genes) as X and X^2; scalar LDS writes
        // (stride 41 keeps compute reads conflict-free; float4 global loads)
        for (int f = t; f < 640; f += 128) {
            int row = f / 10;
            int fc  = (f % 10) * 4;
            int n   = rowbase + row;
            float4 v = make_float4(0.f, 0.f, 0.f, 0.f);
            if (n < N_CELLS) v = *(const float4*)&X[(size_t)n * G_GENES + kt + fc];
            float* xp  = &Xt [row * TSTRIDE + fc];
            float* x2p = &Xt2[row * TSTRIDE + fc];
            xp[0] = v.x; xp[1] = v.y; xp[2] = v.z; xp[3] = v.w;
            x2p[0] = v.x * v.x; x2p[1] = v.y * v.y; x2p[2] = v.z * v.z; x2p[3] = v.w * v.w;
        }
        // stage Coef tile (80 x 40)
        for (int f = t; f < 800; f += 128) {
            int row = f / 10;
            int fc  = (f % 10) * 4;
            float4 v = *(const float4*)&Coef[row * G_GENES + kt + fc];
            float* cp = &Ct[row * TSTRIDE + fc];
            cp[0] = v.x; cp[1] = v.y; cp[2] = v.z; cp[3] = v.w;
        }
        __syncthreads();

        const float* xbase = isA ? Xt2 : Xt;
#pragma unroll 8
        for (int k = 0; k < KT; k++) {
            float xv[8], cv[5];
#pragma unroll
            for (int i = 0; i < 8; i++) xv[i] = xbase[(rg * 8 + i) * TSTRIDE + k];
#pragma unroll
            for (int j = 0; j < 5; j++) cv[j] = Ct[(cg * 5 + j) * TSTRIDE + k];
#pragma unroll
            for (int i = 0; i < 8; i++)
#pragma unroll
                for (int j = 0; j < 5; j++) acc[i][j] += xv[i] * cv[j];
        }
    }

    __syncthreads();
    // dump accumulators to LDS out-buffer (reuses tile space; stride 81)
    float* ob = smem;
#pragma unroll
    for (int i = 0; i < 8; i++)
#pragma unroll
        for (int j = 0; j < 5; j++)
            ob[(rg * 8 + i) * OSTRIDE + cg * 5 + j] = acc[i][j];
    __syncthreads();

    // Phase 2: one lane per row (wave 0 only)
    float llrow = 0.f;
    if (t < 64) {
        int n = rowbase + t;
        if (n < N_CELLS) {
            float w[30];
            float m = -1e30f;
#pragma unroll
            for (int c = 0; c < 30; c++) { w[c] = W[n * 30 + c]; m = fmaxf(m, w[c]); }
            float s = 0.f;
#pragma unroll
            for (int c = 0; c < 30; c++) { w[c] = expf(w[c] - m); s += w[c]; }
            float inv = 1.0f / s;
            float Sn  = S[n];
            float Sn2 = Sn * Sn;
#pragma unroll
            for (int c = 0; c < 30; c++) {
                float p = w[c] * inv;
                out[2 + (size_t)n * 30 + c] = p;
                logP[(size_t)n * 30 + c] = logf(p + 1e-8f);
                float Av = ob[t * OSTRIDE + c];
                float Bv = ob[t * OSTRIDE + 30 + c];
                float F  = -0.5f * (Av - 2.0f * Sn * Bv + Sn2 * Dvec[c]);
                llrow += p * F;
            }
#pragma unroll
            for (int o = 0; o < 8; o++) {
                xl[(size_t)n * 8 + o] = ob[t * OSTRIDE + 60 + o] + bl[o];
                xr[(size_t)n * 8 + o] = ob[t * OSTRIDE + 68 + o] + br[o];
            }
        }
        // wave(64) reduction of llrow, then one atomic per block
        for (int off = 32; off > 0; off >>= 1) llrow += __shfl_down(llrow, off, 64);
        if (t == 0) atomicAdd(&out[0], llrow * (1.0f / N_CELLS));
    }
}

// ---------------------------------------------------------------------------
// K3: per-edge attention logits + segment max over dst
// ---------------------------------------------------------------------------
__global__ void edge_pass1(const int* __restrict__ ei, const float* __restrict__ xl,
                           const float* __restrict__ xr, const float* __restrict__ att,
                           float* __restrict__ evals, unsigned* __restrict__ nodemax) {
    int e = blockIdx.x * 256 + threadIdx.x;
    if (e >= E_EDGES) return;
    int src = ei[e];
    int dst = ei[E_EDGES + e];
    const float4* lp = (const float4*)&xl[(size_t)src * 8];
    const float4* rp = (const float4*)&xr[(size_t)dst * 8];
    float4 l0 = lp[0], l1 = lp[1];
    float4 r0 = rp[0], r1 = rp[1];
    float ev = 0.f;
    ev += lrelu02(l0.x + r0.x) * att[0];
    ev += lrelu02(l0.y + r0.y) * att[1];
    ev += lrelu02(l0.z + r0.z) * att[2];
    ev += lrelu02(l0.w + r0.w) * att[3];
    ev += lrelu02(l1.x + r1.x) * att[4];
    ev += lrelu02(l1.y + r1.y) * att[5];
    ev += lrelu02(l1.z + r1.z) * att[6];
    ev += lrelu02(l1.w + r1.w) * att[7];
    evals[e] = ev;
    atomicMax(&nodemax[dst], fenc(ev));
}

// ---------------------------------------------------------------------------
// K4: exp(e - emax[dst]) and segment sum (denominator)
// ---------------------------------------------------------------------------
__global__ void edge_pass2(const int* __restrict__ ei, const float* __restrict__ evals,
                           const unsigned* __restrict__ nodemax, float* __restrict__ denom) {
    int e = blockIdx.x * 256 + threadIdx.x;
    if (e >= E_EDGES) return;
    int dst = ei[E_EDGES + e];
    float p = __expf(evals[e] - fdec(nodemax[dst]));
    atomicAdd(&denom[dst], p);
}

// ---------------------------------------------------------------------------
// K5: alpha + cross-entropy accumulation (block-reduced)
// ---------------------------------------------------------------------------
__global__ void edge_pass3(const int* __restrict__ ei, const float* __restrict__ evals,
                           const unsigned* __restrict__ nodemax, const float* __restrict__ denom,
                           const float* __restrict__ P, const float* __restrict__ logP,
                           float* __restrict__ out) {
    int e = blockIdx.x * 256 + threadIdx.x;
    float contrib = 0.f;
    if (e < E_EDGES) {
        int src = ei[e];
        int dst = ei[E_EDGES + e];
        float alpha = __expf(evals[e] - fdec(nodemax[dst])) / (denom[dst] + 1e-16f);
        const float2* ps = (const float2*)&P[(size_t)src * 30];
        const float2* ld = (const float2*)&logP[(size_t)dst * 30];
        float dot = 0.f;
#pragma unroll
        for (int c = 0; c < 15; c++) {
            float2 a = ps[c];
            float2 b = ld[c];
            dot += a.x * b.x + a.y * b.y;
        }
        contrib = -alpha * dot;
    }
    // block reduce: per-wave shuffle, then across 4 waves via LDS
    for (int off = 32; off > 0; off >>= 1) contrib += __shfl_down(contrib, off, 64);
    __shared__ float wsum[4];
    int lane = threadIdx.x & 63;
    int wid  = threadIdx.x >> 6;
    if (lane == 0) wsum[wid] = contrib;
    __syncthreads();
    if (threadIdx.x == 0) {
        float ssum = wsum[0] + wsum[1] + wsum[2] + wsum[3];
        atomicAdd(&out[1], ssum * (1.0f / N_CELLS));
    }
}

// ---------------------------------------------------------------------------
// launch
// ---------------------------------------------------------------------------
extern "C" void kernel_launch(void* const* d_in, const int* in_sizes, int n_in,
                              void* d_out, int out_size, void* d_ws, size_t ws_size,
                              hipStream_t stream) {
    const float* X   = (const float*)d_in[0];
    const float* Mu  = (const float*)d_in[1];
    const float* Var = (const float*)d_in[2];
    const int*   ei  = (const int*)d_in[3];
    const float* W   = (const float*)d_in[4];
    const float* S   = (const float*)d_in[5];
    const float* Wl  = (const float*)d_in[6];
    const float* bl  = (const float*)d_in[7];
    const float* Wr  = (const float*)d_in[8];
    const float* br  = (const float*)d_in[9];
    const float* att = (const float*)d_in[10];

    float* out = (float*)d_out;

    // ws layout (floats); total ~13.2 MB
    float* wsf      = (float*)d_ws;
    float* Coef     = wsf;                 // 80*1000      = 80000
    float* Dvec     = wsf + 80000;         // 32
    float* logP     = wsf + 80032;         // N*30         = 1500000
    float* xl       = wsf + 1580032;       // N*8          = 400000
    float* xr       = wsf + 1980032;       // N*8          = 400000
    float* evals    = wsf + 2380032;       // E            = 800000
    float* denom    = wsf + 3180032;       // N            = 50000
    unsigned* nodemax = (unsigned*)(wsf + 3230032); // N   = 50000

    // zero accumulators (denom + nodemax are contiguous -> one memset)
    hipMemsetAsync(out, 0, 2 * sizeof(float), stream);
    hipMemsetAsync(denom, 0, 2 * (size_t)N_CELLS * sizeof(float), stream);

    prep_kernel<<<80, 256, 0, stream>>>(Mu, Var, Wl, Wr, Coef, Dvec);
    main_rows_kernel<<<(N_CELLS + ROWS_PER_BLK - 1) / ROWS_PER_BLK, 128, 0, stream>>>(
        X, W, S, bl, br, Coef, Dvec, out, logP, xl, xr);
    edge_pass1<<<(E_EDGES + 255) / 256, 256, 0, stream>>>(ei, xl, xr, att, evals, nodemax);
    edge_pass2<<<(E_EDGES + 255) / 256, 256, 0, stream>>>(ei, evals, nodemax, denom);
    edge_pass3<<<(E_EDGES + 255) / 256, 256, 0, stream>>>(ei, evals, nodemax, denom,
                                                          out + 2, logP, out);
}

// Round 2
// 461.295 us; speedup vs baseline: 1.4157x; 1.4157x over previous
//
#include <hip/hip_runtime.h>
#include <math.h>

// Problem constants
#define N_CELLS 50000
#define C_CLS   30
#define G_GENES 1000
#define E_EDGES 800000
#define KPAD    1024

// MFMA frag types (per guide: 8 bf16 = short8, 4 fp32 acc)
typedef __attribute__((ext_vector_type(8))) short bf16x8;
typedef __attribute__((ext_vector_type(4))) float f32x4;

// fp32 -> bf16 (RNE), as raw ushort payload
__device__ __forceinline__ unsigned f2bf_u(float f) {
    unsigned u = __float_as_uint(f);
    return (u + 0x7fffu + ((u >> 16) & 1u)) >> 16;
}
__device__ __forceinline__ unsigned pack2(float lo, float hi) {
    return f2bf_u(lo) | (f2bf_u(hi) << 16);
}

__device__ __forceinline__ float lrelu02(float v) { return v > 0.f ? v : 0.2f * v; }

// ---------------------------------------------------------------------------
// K0: pack CoefB bf16 [80][1024]:
//   rows 0..29  : 1/Var        (X^2 GEMM, cols 0..29)   rows 30,31: 0
//   rows 32..61 : Mu/Var       (X GEMM, B part)
//   rows 62..69 : Wl ; rows 70..77 : Wr ; rows 78,79: 0
//   k >= 1000 zero-padded. Also Dvec[30] = sum Mu^2/Var (fp32).
// ---------------------------------------------------------------------------
__global__ void prep_kernel(const float* __restrict__ Mu, const float* __restrict__ Var,
                            const float* __restrict__ Wl, const float* __restrict__ Wr,
                            unsigned short* __restrict__ CoefB, float* __restrict__ Dvec) {
    const int r = blockIdx.x;
    const int t = threadIdx.x;
    __shared__ float red[256];
    float dacc = 0.f;
    for (int g = t; g < KPAD; g += 256) {
        float v = 0.f;
        if (g < G_GENES) {
            if (r < 30) {
                float iv = 1.0f / Var[r * G_GENES + g];
                float mu = Mu[r * G_GENES + g];
                v = iv;
                dacc += mu * mu * iv;
            } else if (r >= 32) {
                int i = r - 32;
                if (i < 30)      v = Mu[i * G_GENES + g] / Var[i * G_GENES + g];
                else if (i < 38) v = Wl[(i - 30) * G_GENES + g];
                else if (i < 46) v = Wr[(i - 38) * G_GENES + g];
            }
        }
        CoefB[r * KPAD + g] = (unsigned short)f2bf_u(v);
    }
    if (r < 30) {
        red[t] = dacc;
        __syncthreads();
        for (int s = 128; s > 0; s >>= 1) {
            if (t < s) red[t] += red[t + s];
            __syncthreads();
        }
        if (t == 0) Dvec[r] = red[0];
    }
}

// ---------------------------------------------------------------------------
// K1: MFMA row kernel. 64 rows/block, 256 threads (4 waves).
// Wave w computes rows w*16..w*16+15 x 80 packed cols via 5 N-tiles of
// mfma_f32_16x16x32_bf16 (tiles 0,1 use X^2 frags, tiles 2..4 use X frags).
// Epilogue: softmax(W) -> P,logP ; F combine -> ll ; xl/xr + bias.
// ---------------------------------------------------------------------------
__global__ __launch_bounds__(256) void main_rows_kernel(
    const float* __restrict__ X, const float* __restrict__ W,
    const float* __restrict__ S, const float* __restrict__ bl,
    const float* __restrict__ br, const unsigned short* __restrict__ CoefB,
    const float* __restrict__ Dvec,
    float* __restrict__ out,          // [0]=ll, [1]=ce, [2..] = P row-major
    float* __restrict__ logP, float* __restrict__ xl, float* __restrict__ xr)
{
    __shared__ __align__(16) char smem[30720];
    unsigned short* Xt  = (unsigned short*)smem;             // [64][72] bf16
    unsigned short* X2t = (unsigned short*)(smem + 9216);    // [64][72] bf16
    unsigned short* Ct  = (unsigned short*)(smem + 18432);   // [80][72] bf16
    float* ob = (float*)smem;                                // [64][81] fp32 (reuse)

    const int t    = threadIdx.x;
    const int w    = t >> 6;
    const int l    = t & 63;
    const int l15  = l & 15;
    const int quad = l >> 4;
    const int rowbase = blockIdx.x * 64;

    f32x4 acc[5];
#pragma unroll
    for (int i = 0; i < 5; i++) acc[i] = (f32x4){0.f, 0.f, 0.f, 0.f};

    // staging assignment: thread -> (row, 16-k quarter)
    const int srow = t >> 2;
    const int sq   = t & 3;
    const int n_g  = rowbase + srow;
    const bool rowok = (n_g < N_CELLS);
    const float* xrow = X + (size_t)n_g * G_GENES;

    for (int kt = 0; kt < KPAD; kt += 64) {
        __syncthreads();
        // ---- stage X tile: 64 rows x 64 k, fp32 -> bf16 (X and X^2) ----
        {
            const int kb = kt + sq * 16;
            float v[16];
#pragma unroll
            for (int i = 0; i < 4; i++) {
                int k = kb + i * 4;
                float4 f = make_float4(0.f, 0.f, 0.f, 0.f);
                if (rowok && k + 3 < G_GENES) f = *(const float4*)&xrow[k];
                v[i * 4 + 0] = f.x; v[i * 4 + 1] = f.y;
                v[i * 4 + 2] = f.z; v[i * 4 + 3] = f.w;
            }
            unsigned px[8], p2[8];
#pragma unroll
            for (int i = 0; i < 8; i++) {
                px[i] = pack2(v[2 * i], v[2 * i + 1]);
                p2[i] = pack2(v[2 * i] * v[2 * i], v[2 * i + 1] * v[2 * i + 1]);
            }
            int4* dx  = (int4*)&Xt [srow * 72 + sq * 16];
            int4* dx2 = (int4*)&X2t[srow * 72 + sq * 16];
            dx [0] = make_int4(px[0], px[1], px[2], px[3]);
            dx [1] = make_int4(px[4], px[5], px[6], px[7]);
            dx2[0] = make_int4(p2[0], p2[1], p2[2], p2[3]);
            dx2[1] = make_int4(p2[4], p2[5], p2[6], p2[7]);
        }
        // ---- stage Coef tile: 80 rows x 64 k bf16, raw 16B copies ----
        for (int u = t; u < 640; u += 256) {
            int row = u >> 3;
            int kk  = (u & 7) * 8;
            *(int4*)&Ct[row * 72 + kk] = *(const int4*)&CoefB[row * KPAD + kt + kk];
        }
        __syncthreads();

        // ---- MFMA: 2 k-steps of 32 ----
#pragma unroll
        for (int ks = 0; ks < 2; ks++) {
            const int koff = ks * 32 + quad * 8;
            bf16x8 ax  = *(bf16x8*)&Xt [(w * 16 + l15) * 72 + koff];
            bf16x8 ax2 = *(bf16x8*)&X2t[(w * 16 + l15) * 72 + koff];
#pragma unroll
            for (int nt = 0; nt < 5; nt++) {
                bf16x8 b = *(bf16x8*)&Ct[(nt * 16 + l15) * 72 + koff];
                acc[nt] = __builtin_amdgcn_mfma_f32_16x16x32_bf16(
                    nt < 2 ? ax2 : ax, b, acc[nt], 0, 0, 0);
            }
        }
    }

    __syncthreads();
    // dump accumulators: C/D layout col=lane&15, row=quad*4+reg
#pragma unroll
    for (int nt = 0; nt < 5; nt++)
#pragma unroll
        for (int r = 0; r < 4; r++)
            ob[(w * 16 + quad * 4 + r) * 81 + nt * 16 + l15] = acc[nt][r];
    __syncthreads();

    // Phase 2: wave 0, one lane per row
    if (t < 64) {
        float llrow = 0.f;
        int n = rowbase + t;
        if (n < N_CELLS) {
            float wv[30];
            const float2* wrow = (const float2*)&W[(size_t)n * 30];
            float m = -1e30f;
#pragma unroll
            for (int c = 0; c < 15; c++) {
                float2 f = wrow[c];
                wv[2 * c] = f.x; wv[2 * c + 1] = f.y;
                m = fmaxf(m, fmaxf(f.x, f.y));
            }
            float s = 0.f;
#pragma unroll
            for (int c = 0; c < 30; c++) { wv[c] = expf(wv[c] - m); s += wv[c]; }
            float inv = 1.0f / s;
            float Sn  = S[n];
            float Sn2 = Sn * Sn;
#pragma unroll
            for (int c = 0; c < 30; c++) {
                float p = wv[c] * inv;
                out[2 + (size_t)n * 30 + c] = p;
                logP[(size_t)n * 30 + c] = logf(p + 1e-8f);
                float Av = ob[t * 81 + c];
                float Bv = ob[t * 81 + 32 + c];
                float F  = -0.5f * (Av - 2.0f * Sn * Bv + Sn2 * Dvec[c]);
                llrow += p * F;
            }
#pragma unroll
            for (int o = 0; o < 8; o++) {
                xl[(size_t)n * 8 + o] = ob[t * 81 + 62 + o] + bl[o];
                xr[(size_t)n * 8 + o] = ob[t * 81 + 70 + o] + br[o];
            }
        }
        for (int off = 32; off > 0; off >>= 1) llrow += __shfl_down(llrow, off, 64);
        if (t == 0) atomicAdd(&out[0], llrow * (1.0f / N_CELLS));
    }
}

// ---------------------------------------------------------------------------
// K2: edge pass A — e-values, exp (no max-subtraction needed: |e| ~ O(10)),
// store p=exp(e), accumulate denom[dst].
// ---------------------------------------------------------------------------
__global__ void edge_passA(const int* __restrict__ ei, const float* __restrict__ xl,
                           const float* __restrict__ xr, const float* __restrict__ att,
                           float* __restrict__ evals, float* __restrict__ denom) {
    int e = blockIdx.x * 256 + threadIdx.x;
    if (e >= E_EDGES) return;
    int src = ei[e];
    int dst = ei[E_EDGES + e];
    const float4* lp = (const float4*)&xl[(size_t)src * 8];
    const float4* rp = (const float4*)&xr[(size_t)dst * 8];
    float4 l0 = lp[0], l1 = lp[1];
    float4 r0 = rp[0], r1 = rp[1];
    float ev = 0.f;
    ev += lrelu02(l0.x + r0.x) * att[0];
    ev += lrelu02(l0.y + r0.y) * att[1];
    ev += lrelu02(l0.z + r0.z) * att[2];
    ev += lrelu02(l0.w + r0.w) * att[3];
    ev += lrelu02(l1.x + r1.x) * att[4];
    ev += lrelu02(l1.y + r1.y) * att[5];
    ev += lrelu02(l1.z + r1.z) * att[6];
    ev += lrelu02(l1.w + r1.w) * att[7];
    float p = __expf(ev);
    evals[e] = p;
    atomicAdd(&denom[dst], p);
}

// ---------------------------------------------------------------------------
// K3: edge pass B — alpha + cross-entropy accumulation (block-reduced)
// ---------------------------------------------------------------------------
__global__ void edge_passB(const int* __restrict__ ei, const float* __restrict__ evals,
                           const float* __restrict__ denom,
                           const float* __restrict__ P, const float* __restrict__ logP,
                           float* __restrict__ out) {
    int e = blockIdx.x * 256 + threadIdx.x;
    float contrib = 0.f;
    if (e < E_EDGES) {
        int src = ei[e];
        int dst = ei[E_EDGES + e];
        float alpha = evals[e] / (denom[dst] + 1e-16f);
        const float2* ps = (const float2*)&P[(size_t)src * 30];
        const float2* ld = (const float2*)&logP[(size_t)dst * 30];
        float dot = 0.f;
#pragma unroll
        for (int c = 0; c < 15; c++) {
            float2 a = ps[c];
            float2 b = ld[c];
            dot += a.x * b.x + a.y * b.y;
        }
        contrib = -alpha * dot;
    }
    for (int off = 32; off > 0; off >>= 1) contrib += __shfl_down(contrib, off, 64);
    __shared__ float wsum[4];
    int lane = threadIdx.x & 63;
    int wid  = threadIdx.x >> 6;
    if (lane == 0) wsum[wid] = contrib;
    __syncthreads();
    if (threadIdx.x == 0) {
        float ssum = wsum[0] + wsum[1] + wsum[2] + wsum[3];
        atomicAdd(&out[1], ssum * (1.0f / N_CELLS));
    }
}

// ---------------------------------------------------------------------------
// launch
// ---------------------------------------------------------------------------
extern "C" void kernel_launch(void* const* d_in, const int* in_sizes, int n_in,
                              void* d_out, int out_size, void* d_ws, size_t ws_size,
                              hipStream_t stream) {
    const float* X   = (const float*)d_in[0];
    const float* Mu  = (const float*)d_in[1];
    const float* Var = (const float*)d_in[2];
    const int*   ei  = (const int*)d_in[3];
    const float* W   = (const float*)d_in[4];
    const float* S   = (const float*)d_in[5];
    const float* Wl  = (const float*)d_in[6];
    const float* bl  = (const float*)d_in[7];
    const float* Wr  = (const float*)d_in[8];
    const float* br  = (const float*)d_in[9];
    const float* att = (const float*)d_in[10];

    float* out = (float*)d_out;

    // ws layout (floats)
    float* wsf   = (float*)d_ws;
    unsigned short* CoefB = (unsigned short*)wsf;   // 80*1024 bf16 = 40960 floats-worth/2
    float* Dvec  = wsf + 40960;                     // 32
    float* logP  = wsf + 40992;                     // N*30 = 1500000
    float* xl    = wsf + 1540992;                   // N*8
    float* xr    = wsf + 1940992;                   // N*8
    float* evals = wsf + 2340992;                   // E
    float* denom = wsf + 3140992;                   // N

    hipMemsetAsync(out, 0, 2 * sizeof(float), stream);
    hipMemsetAsync(denom, 0, (size_t)N_CELLS * sizeof(float), stream);

    prep_kernel<<<80, 256, 0, stream>>>(Mu, Var, Wl, Wr, CoefB, Dvec);
    main_rows_kernel<<<(N_CELLS + 63) / 64, 256, 0, stream>>>(
        X, W, S, bl, br, CoefB, Dvec, out, logP, xl, xr);
    edge_passA<<<(E_EDGES + 255) / 256, 256, 0, stream>>>(ei, xl, xr, att, evals, denom);
    edge_passB<<<(E_EDGES + 255) / 256, 256, 0, stream>>>(ei, evals, denom, out + 2, logP, out);
}